// Round 18
// baseline (2248.604 us; speedup 1.0000x reference)
//
#include <hip/hip_runtime.h>
#include <hip/hip_bf16.h>
#include <hip/hip_fp16.h>

typedef _Float16 f16;
typedef __attribute__((ext_vector_type(4))) _Float16 f16x4;
typedef __attribute__((ext_vector_type(8))) _Float16 f16x8;
typedef __attribute__((ext_vector_type(4))) float f32x4;

#define T_ 512
#define B_ 128
#define I_ 256
#define H_ 512
#define XOFF 544
#define KA2 544     // Wat2 cols: [0,512) W_att | 512 b_att | 0
#define NFRAG 78    // 26 k-tiles x 3 gates per c-slice
#define TP 20

#define MFMA16(a,b,c) __builtin_amdgcn_mfma_f32_16x16x32_f16((a),(b),(c),0,0,0)

__device__ __forceinline__ float fast_exp(float x){
  return __builtin_amdgcn_exp2f(x * 1.4426950408889634f);
}
__device__ __forceinline__ float sigm(float x){
  return __builtin_amdgcn_rcpf(1.f + fast_exp(-x));
}
__device__ __forceinline__ float tanh_f(float x){
  return 1.f - 2.f * __builtin_amdgcn_rcpf(1.f + fast_exp(2.f * x));
}

// ---------------- prep: x16 + Wat2 + WlinG (fragment-linear weights, direct) ----------------
// WlinG[c][f][lane][8]: f = kt*3+gate; source col k = kt*32 + lg*8 + e with the Wc2 rule:
// [0,512) W_hh | 512 b_hh | 0 | [544,800) W_ih | 800 b_ih | 0 ; row r = gate*H + c*16 + l16.
__global__ void k_prep(const float* __restrict__ x, const float* __restrict__ Wih,
                       const float* __restrict__ Whh,
                       const float* __restrict__ bih, const float* __restrict__ bhh,
                       const float* __restrict__ Watt, const float* __restrict__ batt,
                       f16* __restrict__ WlinG, f16* __restrict__ Wat2, f16* __restrict__ x16){
  const int n1 = B_ * T_ * I_;
  const int n2 = H_ * KA2;
  const int n3 = 32 * NFRAG * 64 * 8;
  const int tot = n1 + n2 + n3;
  for (int i = blockIdx.x * blockDim.x + threadIdx.x; i < tot; i += gridDim.x * blockDim.x){
    if (i < n1){
      x16[i] = (f16)x[i];
    } else if (i < n1 + n2){
      int j = i - n1; int r = j / KA2, k = j % KA2;
      float v = (k < H_) ? Watt[r * H_ + k] : (k == H_ ? batt[r] : 0.f);
      Wat2[j] = (f16)v;
    } else {
      int j = i - n1 - n2;
      int chunk = j >> 3, e = j & 7;
      int c = chunk / (NFRAG * 64);
      int rem = chunk - c * (NFRAG * 64);
      int f = rem >> 6, lane = rem & 63;
      int l16 = lane & 15, lg = lane >> 4;
      int kt = f / 3, gi = f - 3 * kt;
      int r = gi * H_ + c * 16 + l16;
      int k = kt * 32 + lg * 8 + e;
      float v;
      if      (k <  H_)   v = Whh[r * H_ + k];
      else if (k == H_)   v = bhh[r];
      else if (k <  XOFF) v = 0.f;
      else if (k <  800)  v = Wih[r * I_ + (k - XOFF)];
      else if (k == 800)  v = bih[r];
      else                v = 0.f;
      WlinG[j] = (f16)v;
    }
  }
}

// ---------------- probe: (lane,reg)->(row,col) D mapping ----------------
__global__ void k_probe(int* __restrict__ rtab, int* __restrict__ ctab){
  __shared__ __align__(16) f16 A[16][32];
  __shared__ __align__(16) f16 BT[16][32];
  const int l = threadIdx.x, l16 = l & 15, lg = l >> 4;
  for (int i = l; i < 512; i += 64){ ((f16*)A)[i] = (f16)0.f; ((f16*)BT)[i] = (f16)0.f; }
  __syncthreads();
  if (l < 16){
    A[l][0]  = (f16)(float)(16 * l);
    A[l][1]  = (f16)1.f;
    BT[l][0] = (f16)1.f;
    BT[l][1] = (f16)(float)l;
  }
  __syncthreads();
  f16x8 a = *(const f16x8*)&A[l16][lg * 8];
  f16x8 b = *(const f16x8*)&BT[l16][lg * 8];
  f32x4 z; z[0]=0.f; z[1]=0.f; z[2]=0.f; z[3]=0.f;
  f32x4 d = MFMA16(a, b, z);
  #pragma unroll
  for (int q = 0; q < 4; ++q){
    int code = (int)(d[q] + 0.5f);
    rtab[l * 4 + q] = code >> 4;
    ctab[l * 4 + q] = code & 15;
  }
}

// ---------------- x-part precompute for a 32-step chunk (r14-proven) ------------------------
// gx'[tl][g][c][gate][lane*4+q] = (x(t0+tl) @ Wih^T + b_ih (+ b_hh for R,Z)) at D-slot (lane,q)
__global__ __launch_bounds__(256, 1) void k_xg(int t0, const f16* __restrict__ x16,
    const f16* __restrict__ WlinG, f16* __restrict__ gxl){
  const int tid = threadIdx.x, wv = tid >> 6, lane = tid & 63, l16 = lane & 15, lg = lane >> 4;
  const int wid = blockIdx.x * 4 + wv;     // 0..1023
  const int tq = wid & 3;
  const int c  = (wid >> 2) & 31;
  const int g  = wid >> 7;
  const int b0 = g * 16;

  f16x8 ones;
  #pragma unroll
  for (int e = 0; e < 8; ++e) ones[e] = (f16)0.f;
  if (lg == 0) ones[0] = (f16)1.f;

  const f16* wb = WlinG + ((size_t)c * NFRAG * 64 + lane) * 8;
  f16x8 bw[3][10];
  #pragma unroll
  for (int gate = 0; gate < 3; ++gate){
    #pragma unroll
    for (int kx = 0; kx < 8; ++kx)
      bw[gate][kx] = *(const f16x8*)(wb + (size_t)((17 + kx) * 3 + gate) * 512);
    bw[gate][8] = *(const f16x8*)(wb + (size_t)(25 * 3 + gate) * 512);   // b_ih
    if (gate < 2)
      bw[gate][9] = *(const f16x8*)(wb + (size_t)(16 * 3 + gate) * 512); // b_hh (R,Z only)
  }

  for (int tl = tq * 8; tl < tq * 8 + 8; ++tl){
    const int t = t0 + tl;
    f16x8 a[8];
    const f16* xrow = x16 + ((size_t)(b0 + l16) * T_ + t) * I_ + lg * 8;
    #pragma unroll
    for (int kx = 0; kx < 8; ++kx) a[kx] = *(const f16x8*)(xrow + kx * 32);

    #pragma unroll
    for (int gate = 0; gate < 3; ++gate){
      f32x4 acc;
      #pragma unroll
      for (int q = 0; q < 4; ++q) acc[q] = 0.f;
      #pragma unroll
      for (int kx = 0; kx < 8; ++kx) acc = MFMA16(a[kx], bw[gate][kx], acc);
      acc = MFMA16(ones, bw[gate][8], acc);
      if (gate < 2) acc = MFMA16(ones, bw[gate][9], acc);
      f16x4 o;
      #pragma unroll
      for (int q = 0; q < 4; ++q) o[q] = (f16)acc[q];
      *(f16x4*)(gxl + ((((size_t)tl * 8 + g) * 32 + c) * 3 + gate) * 256 + lane * 4) = o;
    }
  }
}

// ---------------- one recurrence step (h-part only), 2-wave k-split (r14/r16-proven) --------
__global__ __launch_bounds__(128) void k_step(int t, const f16* __restrict__ gx,
    const f16* __restrict__ WlinG, const float* __restrict__ bhh,
    const int* __restrict__ rtab, const int* __restrict__ ctab,
    const f16* __restrict__ hin, f16* __restrict__ hout, f16* __restrict__ hs){
  const int bid = blockIdx.x;
  const int g = bid & 7, c = bid >> 3;
  const int b0 = g * 16, j0 = c * 16;
  const int tid = threadIdx.x, w = tid >> 6, lane = tid & 63, l16 = lane & 15, lg = lane >> 4;

  __shared__ __align__(16) float part[64][13];
  __shared__ __align__(16) f16 ttile[16 * TP];

  int rt[4], ct[4];
  #pragma unroll
  for (int q = 0; q < 4; ++q){ rt[q] = rtab[lane*4+q]; ct[q] = ctab[lane*4+q]; }

  // wave 0: issue epilogue operands early (overlap with MFMA loop)
  f16x4 gR, gZ, gN;
  float hold[4], bnhv[4];
  #pragma unroll
  for (int q = 0; q < 4; ++q){ hold[q] = 0.f; bnhv[q] = 0.f; }
  if (w == 0){
    const f16* gp = gx + ((((size_t)(t & 31)) * 8 + g) * 32 + c) * 3 * 256;
    gR = *(const f16x4*)(gp + 0 * 256 + lane * 4);
    gZ = *(const f16x4*)(gp + 1 * 256 + lane * 4);
    gN = *(const f16x4*)(gp + 2 * 256 + lane * 4);
    #pragma unroll
    for (int q = 0; q < 4; ++q){
      hold[q] = (float)hin[(size_t)(b0 + rt[q]) * H_ + j0 + ct[q]];
      bnhv[q] = bhh[2 * H_ + j0 + ct[q]];
    }
  }

  const f16* wbase = WlinG + ((size_t)c * NFRAG * 64 + lane) * 8;
  const f16* hrow  = hin + (size_t)(b0 + l16) * H_ + lg * 8;

  f32x4 aR, aZ, aNh;
  #pragma unroll
  for (int q = 0; q < 4; ++q){ aR[q] = 0.f; aZ[q] = 0.f; aNh[q] = 0.f; }

  const int k0 = w * 8;
  #pragma unroll
  for (int kt = 0; kt < 8; ++kt){
    const int kk = k0 + kt;
    f16x8 a  = *(const f16x8*)(hrow + kk * 32);
    f16x8 w0 = *(const f16x8*)(wbase + (size_t)(kk*3+0) * 512);
    f16x8 w1 = *(const f16x8*)(wbase + (size_t)(kk*3+1) * 512);
    f16x8 w2 = *(const f16x8*)(wbase + (size_t)(kk*3+2) * 512);
    aR  = MFMA16(a, w0, aR);
    aZ  = MFMA16(a, w1, aZ);
    aNh = MFMA16(a, w2, aNh);
  }

  if (w == 1){
    #pragma unroll
    for (int q = 0; q < 4; ++q){
      part[lane][q]     = aR[q];
      part[lane][4 + q] = aZ[q];
      part[lane][8 + q] = aNh[q];
    }
  }
  __syncthreads();

  if (w == 0){
    #pragma unroll
    for (int q = 0; q < 4; ++q){
      float R  = aR[q]  + part[lane][q]     + (float)gR[q];
      float Z  = aZ[q]  + part[lane][4 + q] + (float)gZ[q];
      float Nh = aNh[q] + part[lane][8 + q] + bnhv[q];
      float r  = sigm(R);
      float z  = sigm(Z);
      float nn = tanh_f((float)gN[q] + r * Nh);
      float h  = (1.f - z) * nn + z * hold[q];
      ttile[rt[q] * TP + ct[q]] = (f16)h;
    }
    asm volatile("s_waitcnt lgkmcnt(0)" ::: "memory");
    const int rr = lane >> 2, c4 = (lane & 3) * 4;
    f16x4 tv = *(const f16x4*)&ttile[rr * TP + c4];
    unsigned long long pk;
    __builtin_memcpy(&pk, &tv, 8);
    *(unsigned long long*)(hout + (size_t)(b0 + rr) * H_ + j0 + c4) = pk;
    *(unsigned long long*)(hs + ((size_t)t * B_ + b0 + rr) * H_ + j0 + c4) = pk;
  }
}

// ---------------- fused attention (r13/r14/r16-proven) ----------------
__global__ __launch_bounds__(256, 1) void k_att(const f16* __restrict__ hs,
    const f16* __restrict__ Wat2, const int* __restrict__ rtab, const int* __restrict__ ctab,
    float* __restrict__ out){
  const int b  = blockIdx.x >> 1;
  const int jh = blockIdx.x & 1;
  const int tid = threadIdx.x, wv = tid >> 6, lane = tid & 63, l16 = lane & 15, lg = lane >> 4;
  const int jb = jh * 256 + wv * 64;

  __shared__ __align__(16) float etile[4][16 * TP];

  int rt[4], ct[4];
  #pragma unroll
  for (int q = 0; q < 4; ++q){ rt[q] = rtab[lane*4+q]; ct[q] = ctab[lane*4+q]; }

  f16x8 ones;
  #pragma unroll
  for (int e = 0; e < 8; ++e) ones[e] = (f16)0.f;
  if (lg == 0) ones[0] = (f16)1.f;

  float num[4][4], den[4][4];
  #pragma unroll
  for (int nt = 0; nt < 4; ++nt)
    #pragma unroll
    for (int k = 0; k < 4; ++k){ num[nt][k] = 0.f; den[nt][k] = 0.f; }

  for (int tt = 0; tt < 32; ++tt){
    f16x8 a[16];
    const f16* ar = hs + ((size_t)(tt*16 + l16) * B_ + b) * H_ + lg * 8;
    #pragma unroll
    for (int kt = 0; kt < 16; ++kt) a[kt] = *(const f16x8*)(ar + kt * 32);

    #pragma unroll
    for (int nt = 0; nt < 4; ++nt){
      f32x4 acc;
      #pragma unroll
      for (int q = 0; q < 4; ++q) acc[q] = 0.f;
      const f16* wr = Wat2 + (size_t)(jb + nt*16 + l16) * KA2 + lg * 8;
      #pragma unroll
      for (int kt = 0; kt < 16; ++kt){
        f16x8 bf = *(const f16x8*)(wr + kt * 32);
        acc = MFMA16(a[kt], bf, acc);
      }
      { f16x8 bf = *(const f16x8*)(wr + 512); acc = MFMA16(ones, bf, acc); }

      #pragma unroll
      for (int q = 0; q < 4; ++q)
        etile[wv][rt[q] * TP + ct[q]] = fast_exp(tanh_f(acc[q]));
      asm volatile("s_waitcnt lgkmcnt(0)" ::: "memory");
      f32x4 ev = *(const f32x4*)&etile[wv][(lane>>2) * TP + (lane & 3) * 4];
      const f16* hp = hs + ((size_t)(tt*16 + (lane>>2)) * B_ + b) * H_ + jb + nt*16 + (lane&3)*4;
      f16x4 hv = *(const f16x4*)hp;
      #pragma unroll
      for (int k = 0; k < 4; ++k){
        num[nt][k] = fmaf(ev[k], (float)hv[k], num[nt][k]);
        den[nt][k] += ev[k];
      }
    }
  }

  #pragma unroll
  for (int nt = 0; nt < 4; ++nt){
    #pragma unroll
    for (int k = 0; k < 4; ++k){
      float n = num[nt][k], d = den[nt][k];
      #pragma unroll
      for (int m = 4; m <= 32; m <<= 1){ n += __shfl_xor(n, m, 64); d += __shfl_xor(d, m, 64); }
      if (lane < 4) out[(size_t)b * H_ + jb + nt*16 + lane*4 + k] = n / d;
    }
  }
}

extern "C" void kernel_launch(void* const* d_in, const int* in_sizes, int n_in,
                              void* d_out, int out_size, void* d_ws, size_t ws_size,
                              hipStream_t stream){
  (void)in_sizes; (void)n_in; (void)out_size;
  const float* x    = (const float*)d_in[0];
  const float* Wih  = (const float*)d_in[1];
  const float* Whh  = (const float*)d_in[2];
  const float* bih  = (const float*)d_in[3];
  const float* bhh  = (const float*)d_in[4];
  const float* Watt = (const float*)d_in[5];
  const float* batt = (const float*)d_in[6];

  char* ws = (char*)d_ws;
  // layout (bytes):
  //   hs   : [T][B][H] f16            @ 0            (67,108,864)
  //   x16  : [B][T][I] f16            @ 67,108,864   (33,554,432)
  //   WlinG: [32][78][64][8] f16      @ 100,663,296  (2,555,904)
  //   Wat2 : [512][544] f16           @ 103,219,200  (557,056)
  //   rtab : int[256]                 @ 103,776,256  (1,024)
  //   ctab : int[256]                 @ 103,777,280  (1,024)
  //   hA   : [128][512] f16           @ 103,778,304  (131,072)
  //   hB   : [128][512] f16           @ 103,909,376  (131,072)
  //   gx0  : [32][8][32][3][256] f16  @ 104,040,448  (12,582,912)
  //   gx1  : same                     @ 116,623,360  (12,582,912)
  const size_t OFF_HS  = 0ull;
  const size_t OFF_X16 = 67108864ull;
  const size_t OFF_WLG = 100663296ull;
  const size_t OFF_WAT = 103219200ull;
  const size_t OFF_RT  = 103776256ull;
  const size_t OFF_CT  = 103777280ull;
  const size_t OFF_HA  = 103778304ull;
  const size_t OFF_HB  = 103909376ull;
  const size_t OFF_GX0 = 104040448ull;
  const size_t OFF_GX1 = 116623360ull;
  const size_t NEED    = 129206272ull;   // <= 137,332,736 proven available
  if (ws_size < NEED) return;

  f16* hs    = (f16*)(ws + OFF_HS);
  f16* x16   = (f16*)(ws + OFF_X16);
  f16* WlinG = (f16*)(ws + OFF_WLG);
  f16* Wat2  = (f16*)(ws + OFF_WAT);
  int* rtab  = (int*)(ws + OFF_RT);
  int* ctab  = (int*)(ws + OFF_CT);
  f16* hA    = (f16*)(ws + OFF_HA);
  f16* hB    = (f16*)(ws + OFF_HB);
  f16* gxb[2] = { (f16*)(ws + OFF_GX0), (f16*)(ws + OFF_GX1) };

  // h(-1) = 0 every launch
  hipMemsetAsync(ws + OFF_HA, 0, 131072, stream);

  k_prep <<<2048, 256, 0, stream>>>(x, Wih, Whh, bih, bhh, Watt, batt, WlinG, Wat2, x16);
  k_probe<<<1,    64,  0, stream>>>(rtab, ctab);
  k_xg   <<<256,  256, 0, stream>>>(0, x16, WlinG, gxb[0]);

  for (int t = 0; t < T_; ++t){
    const f16* hin  = (t & 1) ? hB : hA;
    f16*       hout = (t & 1) ? hA : hB;
    k_step<<<256, 128, 0, stream>>>(t, gxb[(t >> 5) & 1], WlinG, bhh, rtab, ctab, hin, hout, hs);
    if ((t & 31) == 0 && t + 32 < T_)
      k_xg<<<256, 256, 0, stream>>>(t + 32, x16, WlinG, gxb[((t >> 5) + 1) & 1]);
  }

  k_att<<<256, 256, 0, stream>>>(hs, Wat2, rtab, ctab, (float*)d_out);
}